// Round 1
// baseline (15993.552 us; speedup 1.0000x reference)
//
#include <hip/hip_runtime.h>

#define NN 50000
#define NE 1600000

// workspace layout (float offsets)
#define WS_X0    0
#define WS_X1    (WS_X0 + NN*16)            // 800000
#define WS_HAG   (WS_X1 + NN*16)            // 1600000
#define WS_DEG   (WS_HAG + NN*64)           // 4800000
#define WS_W1TE  (WS_DEG + NN)              // 4850000
#define WS_M     (WS_W1TE + 3*64*32)        // +6144
#define WS_C0    (WS_M + 3*64*4)            // +768
#define WS_W1TN  (WS_C0 + 3*64)             // +192
#define WS_QW    (WS_W1TN + 3*64*32)        // +6144
#define WS_TOTAL (WS_QW + 8)

// ---------------------------------------------------------------------------
// prep: transpose per-layer W1 (edge: rows 0..31 -> [64][32]; node [32][64] ->
// [64][32]), fold edge-embedding into M[4][64] + c0[64], collapse q weights.
// ---------------------------------------------------------------------------
__global__ void prep_kernel(const float* __restrict__ ew1, const float* __restrict__ eb1,
                            const float* __restrict__ nw1,
                            const float* __restrict__ eeW, const float* __restrict__ eeB,
                            const float* __restrict__ few, const float* __restrict__ feb,
                            float* __restrict__ w1te, float* __restrict__ Mm,
                            float* __restrict__ c0, float* __restrict__ w1tn,
                            float* __restrict__ qw)
{
    int t = blockIdx.x * blockDim.x + threadIdx.x;
    int stride = gridDim.x * blockDim.x;
    // transposes: idx -> l, j, i
    for (int idx = t; idx < 3 * 64 * 32; idx += stride) {
        int l = idx / 2048, r = idx % 2048, j = r / 32, i = r % 32;
        w1te[idx] = ew1[l * 3072 + i * 64 + j];   // edge_mlp_w1 [3][48][64], rows 0..31
        w1tn[idx] = nw1[l * 2048 + i * 64 + j];   // node_mlp_w1 [3][32][64]
    }
    // M[l][j][f] = sum_k eeW[f][k] * W1e[l][32+k][j]
    for (int idx = t; idx < 3 * 64 * 4; idx += stride) {
        int l = idx / 256, r = idx % 256, j = r / 4, f = r % 4;
        float s = 0.f;
        for (int k = 0; k < 16; k++) s += eeW[f * 16 + k] * ew1[l * 3072 + (32 + k) * 64 + j];
        Mm[idx] = s;
    }
    // c0[l][j] = b1[l][j] + sum_k eeB[k] * W1e[l][32+k][j]
    for (int idx = t; idx < 3 * 64; idx += stride) {
        int l = idx / 64, j = idx % 64;
        float s = eb1[idx];
        for (int k = 0; k < 16; k++) s += eeB[k] * ew1[l * 3072 + (32 + k) * 64 + j];
        c0[idx] = s;
    }
    // q collapse: q = pa . qw[0..3] + qw[4]
    if (t < 4) {
        float s = 0.f;
        for (int k = 0; k < 16; k++) s += eeW[t * 16 + k] * few[k];
        qw[t] = s;
    } else if (t == 4) {
        float s = feb[0];
        for (int k = 0; k < 16; k++) s += eeB[k] * few[k];
        qw[4] = s;
    }
}

// ---------------------------------------------------------------------------
// node init: x0 = leak * w + b ; zero deg and h-aggregate table
// ---------------------------------------------------------------------------
__global__ __launch_bounds__(256) void node_init_kernel(
    const float* __restrict__ leak, const float* __restrict__ nw, const float* __restrict__ nb,
    float* __restrict__ x0, float* __restrict__ hag, float* __restrict__ degf)
{
    int n = blockIdx.x * blockDim.x + threadIdx.x;
    if (n >= NN) return;
    float la = leak[n];
    float4* xo = reinterpret_cast<float4*>(x0 + n * 16);
    #pragma unroll
    for (int q4 = 0; q4 < 4; q4++) {
        float4 v;
        v.x = la * nw[q4 * 4 + 0] + nb[q4 * 4 + 0];
        v.y = la * nw[q4 * 4 + 1] + nb[q4 * 4 + 1];
        v.z = la * nw[q4 * 4 + 2] + nb[q4 * 4 + 2];
        v.w = la * nw[q4 * 4 + 3] + nb[q4 * 4 + 3];
        xo[q4] = v;
    }
    degf[n] = 0.f;
    float4 z = {0.f, 0.f, 0.f, 0.f};
    float4* hp = reinterpret_cast<float4*>(hag + n * 64);
    #pragma unroll
    for (int j = 0; j < 16; j++) hp[j] = z;
}

// ---------------------------------------------------------------------------
// edge init: q output (collapsed linear) + degree count
// ---------------------------------------------------------------------------
__global__ __launch_bounds__(256) void edge_init_kernel(
    const float* __restrict__ pa, const int* __restrict__ dst,
    const float* __restrict__ qw, float* __restrict__ qout, float* __restrict__ degf)
{
    int t = blockIdx.x * blockDim.x + threadIdx.x;
    if (t >= NE) return;
    float4 p = reinterpret_cast<const float4*>(pa)[t];
    qout[t] = qw[4] + p.x * qw[0] + p.y * qw[1] + p.z * qw[2] + p.w * qw[3];
    unsafeAtomicAdd(&degf[dst[t]], 1.0f);
}

// ---------------------------------------------------------------------------
// edge MLP stage-1 (48->64) with e folded to pa, h aggregated atomically
// per-dst into hag[N][64] (stage-2 W2 hoisted to the node kernel).
// ---------------------------------------------------------------------------
__global__ __launch_bounds__(256) void edge_mlp_kernel(
    const float* __restrict__ x, const int* __restrict__ src, const int* __restrict__ dst,
    const float* __restrict__ pa,
    const float* __restrict__ w1t,  // [64][32]
    const float* __restrict__ Mm,   // [64][4]
    const float* __restrict__ c0,   // [64]
    float* __restrict__ hag)
{
    int t = blockIdx.x * blockDim.x + threadIdx.x;
    if (t >= NE) return;
    int s = src[t], d = dst[t];
    float m[32];
    const float4* xd = reinterpret_cast<const float4*>(x + d * 16);
    const float4* xs = reinterpret_cast<const float4*>(x + s * 16);
    #pragma unroll
    for (int q4 = 0; q4 < 4; q4++) {
        float4 v = xd[q4];
        m[q4 * 4 + 0] = v.x; m[q4 * 4 + 1] = v.y; m[q4 * 4 + 2] = v.z; m[q4 * 4 + 3] = v.w;
    }
    #pragma unroll
    for (int q4 = 0; q4 < 4; q4++) {
        float4 v = xs[q4];
        m[16 + q4 * 4 + 0] = v.x; m[16 + q4 * 4 + 1] = v.y; m[16 + q4 * 4 + 2] = v.z; m[16 + q4 * 4 + 3] = v.w;
    }
    float4 p = reinterpret_cast<const float4*>(pa)[t];
    float* hb = hag + d * 64;
    #pragma unroll 1
    for (int j0 = 0; j0 < 64; j0 += 16) {
        float h[16];
        #pragma unroll
        for (int jj = 0; jj < 16; jj++) {
            int j = j0 + jj;
            float acc = c0[j] + p.x * Mm[j * 4 + 0] + p.y * Mm[j * 4 + 1]
                              + p.z * Mm[j * 4 + 2] + p.w * Mm[j * 4 + 3];
            const float* wr = w1t + j * 32;
            #pragma unroll
            for (int i = 0; i < 32; i++) acc += m[i] * wr[i];
            h[jj] = fmaxf(acc, 0.f);
        }
        #pragma unroll
        for (int jj = 0; jj < 16; jj++) unsafeAtomicAdd(hb + j0 + jj, h[jj]);
    }
}

// ---------------------------------------------------------------------------
// node update: aggr = W2^T(hag)/deg + b2 (0 if deg==0), then 32->64->16 MLP.
// Re-zeros hag for the next layer. Optionally emits H on the last layer.
// ---------------------------------------------------------------------------
__global__ __launch_bounds__(256) void node_mlp_kernel(
    const float* __restrict__ x, float* __restrict__ xn,
    float* __restrict__ hag, const float* __restrict__ degf,
    const float* __restrict__ ew2, const float* __restrict__ eb2,
    const float* __restrict__ nw1t, const float* __restrict__ nb1,
    const float* __restrict__ nw2, const float* __restrict__ nb2,
    const float* __restrict__ fnw, const float* __restrict__ fnb,
    float* __restrict__ Hout, int writeH)
{
    int n = blockIdx.x * blockDim.x + threadIdx.x;
    if (n >= NN) return;
    float u[32];
    const float4* xp = reinterpret_cast<const float4*>(x + n * 16);
    #pragma unroll
    for (int q4 = 0; q4 < 4; q4++) {
        float4 v = xp[q4];
        u[q4 * 4 + 0] = v.x; u[q4 * 4 + 1] = v.y; u[q4 * 4 + 2] = v.z; u[q4 * 4 + 3] = v.w;
    }
    float dg = degf[n];
    float inv = 1.0f / fmaxf(dg, 1.0f);
    float bsc = (dg > 0.f) ? 1.0f : 0.0f;   // reference: aggr==0 when deg==0
    float tacc[16];
    #pragma unroll
    for (int k = 0; k < 16; k++) tacc[k] = 0.f;
    float4* hp4 = reinterpret_cast<float4*>(hag + n * 64);
    #pragma unroll 1
    for (int j4 = 0; j4 < 16; j4++) {
        float4 hv = hp4[j4];
        int j = j4 * 4;
        #pragma unroll
        for (int k = 0; k < 16; k++) {
            tacc[k] += hv.x * ew2[(j + 0) * 16 + k];
            tacc[k] += hv.y * ew2[(j + 1) * 16 + k];
            tacc[k] += hv.z * ew2[(j + 2) * 16 + k];
            tacc[k] += hv.w * ew2[(j + 3) * 16 + k];
        }
    }
    float4 z = {0.f, 0.f, 0.f, 0.f};
    #pragma unroll
    for (int j4 = 0; j4 < 16; j4++) hp4[j4] = z;  // re-zero for next layer
    #pragma unroll
    for (int k = 0; k < 16; k++) u[16 + k] = bsc * eb2[k] + tacc[k] * inv;

    float o[16];
    #pragma unroll
    for (int k = 0; k < 16; k++) o[k] = nb2[k];
    #pragma unroll 1
    for (int j = 0; j < 64; j++) {
        float h = nb1[j];
        const float* wr = nw1t + j * 32;
        #pragma unroll
        for (int i = 0; i < 32; i++) h += u[i] * wr[i];
        h = fmaxf(h, 0.f);
        #pragma unroll
        for (int k = 0; k < 16; k++) o[k] += h * nw2[j * 16 + k];
    }
    float4* xo = reinterpret_cast<float4*>(xn + n * 16);
    #pragma unroll
    for (int q4 = 0; q4 < 4; q4++) {
        float4 v;
        v.x = o[q4 * 4 + 0]; v.y = o[q4 * 4 + 1]; v.z = o[q4 * 4 + 2]; v.w = o[q4 * 4 + 3];
        xo[q4] = v;
    }
    if (writeH) {
        float s = fnb[0];
        #pragma unroll
        for (int k = 0; k < 16; k++) s += o[k] * fnw[k];
        Hout[n] = s;
    }
}

extern "C" void kernel_launch(void* const* d_in, const int* in_sizes, int n_in,
                              void* d_out, int out_size, void* d_ws, size_t ws_size,
                              hipStream_t stream)
{
    const float* leak = (const float*)d_in[0];
    const float* pa   = (const float*)d_in[1];
    const int*   ei   = (const int*)d_in[2];
    const float* neww = (const float*)d_in[3];
    const float* newb = (const float*)d_in[4];
    const float* eeW  = (const float*)d_in[5];
    const float* eeB  = (const float*)d_in[6];
    const float* ew1  = (const float*)d_in[7];
    const float* eb1  = (const float*)d_in[8];
    const float* ew2  = (const float*)d_in[9];
    const float* eb2  = (const float*)d_in[10];
    const float* nw1  = (const float*)d_in[11];
    const float* nb1  = (const float*)d_in[12];
    const float* nw2  = (const float*)d_in[13];
    const float* nb2  = (const float*)d_in[14];
    const float* fnw  = (const float*)d_in[15];
    const float* fnb  = (const float*)d_in[16];
    const float* few  = (const float*)d_in[17];
    const float* feb  = (const float*)d_in[18];

    float* ws   = (float*)d_ws;
    float* x0   = ws + WS_X0;
    float* x1   = ws + WS_X1;
    float* hag  = ws + WS_HAG;
    float* degf = ws + WS_DEG;
    float* w1te = ws + WS_W1TE;
    float* Mm   = ws + WS_M;
    float* c0   = ws + WS_C0;
    float* w1tn = ws + WS_W1TN;
    float* qw   = ws + WS_QW;

    float* H = (float*)d_out;
    float* q = (float*)d_out + NN;
    const int* srcp = ei;
    const int* dstp = ei + NE;

    prep_kernel<<<8, 256, 0, stream>>>(ew1, eb1, nw1, eeW, eeB, few, feb,
                                       w1te, Mm, c0, w1tn, qw);
    node_init_kernel<<<(NN + 255) / 256, 256, 0, stream>>>(leak, neww, newb, x0, hag, degf);
    edge_init_kernel<<<(NE + 255) / 256, 256, 0, stream>>>(pa, dstp, qw, q, degf);

    float* xcur = x0;
    float* xnxt = x1;
    for (int l = 0; l < 3; l++) {
        edge_mlp_kernel<<<(NE + 255) / 256, 256, 0, stream>>>(
            xcur, srcp, dstp, pa, w1te + l * 2048, Mm + l * 256, c0 + l * 64, hag);
        node_mlp_kernel<<<(NN + 255) / 256, 256, 0, stream>>>(
            xcur, xnxt, hag, degf, ew2 + l * 1024, eb2 + l * 16,
            w1tn + l * 2048, nb1 + l * 64, nw2 + l * 1024, nb2 + l * 16,
            fnw, fnb, H, (l == 2) ? 1 : 0);
        float* tmp = xcur; xcur = xnxt; xnxt = tmp;
    }
}

// Round 2
// 875.036 us; speedup vs baseline: 18.2776x; 18.2776x over previous
//
#include <hip/hip_runtime.h>

#define NN 50000
#define NE 1600000

// ---- workspace layout (element offsets; floats then ints) ----
#define WS_X0    0
#define WS_X1    (WS_X0 + NN*16)          // 800000
#define WS_AGGR  (WS_X1 + NN*16)          // 1600000
#define WS_W1TE  (WS_AGGR + NN*16)        // 2400000
#define WS_M     (WS_W1TE + 3*64*32)
#define WS_C0    (WS_M + 3*64*4)
#define WS_W1TN  (WS_C0 + 3*64)
#define WS_QW    (WS_W1TN + 3*64*32)
#define WS_IEND  (WS_QW + 8)
// int region
#define WI_DEG   0
#define WI_CUR   (WI_DEG + NN)
#define WI_OFF   (WI_CUR + NN)            // NN+1 entries
#define WI_PERM  (WI_OFF + NN + 1)
// total = WS_IEND + WI_PERM + NE  ~ 4.17M elems ~ 16.7 MB

// ---------------------------------------------------------------------------
// prep: transpose per-layer W1, fold edge-embedding into M[64][4] + c0[64],
// collapse q weights.
// ---------------------------------------------------------------------------
__global__ void prep_kernel(const float* __restrict__ ew1, const float* __restrict__ eb1,
                            const float* __restrict__ nw1,
                            const float* __restrict__ eeW, const float* __restrict__ eeB,
                            const float* __restrict__ few, const float* __restrict__ feb,
                            float* __restrict__ w1te, float* __restrict__ Mm,
                            float* __restrict__ c0, float* __restrict__ w1tn,
                            float* __restrict__ qw)
{
    int t = blockIdx.x * blockDim.x + threadIdx.x;
    int stride = gridDim.x * blockDim.x;
    for (int idx = t; idx < 3 * 64 * 32; idx += stride) {
        int l = idx / 2048, r = idx % 2048, j = r / 32, i = r % 32;
        w1te[idx] = ew1[l * 3072 + i * 64 + j];   // edge_mlp_w1 [3][48][64], rows 0..31
        w1tn[idx] = nw1[l * 2048 + i * 64 + j];   // node_mlp_w1 [3][32][64]
    }
    for (int idx = t; idx < 3 * 64 * 4; idx += stride) {
        int l = idx / 256, r = idx % 256, j = r / 4, f = r % 4;
        float s = 0.f;
        for (int k = 0; k < 16; k++) s += eeW[f * 16 + k] * ew1[l * 3072 + (32 + k) * 64 + j];
        Mm[idx] = s;
    }
    for (int idx = t; idx < 3 * 64; idx += stride) {
        int l = idx / 64, j = idx % 64;
        float s = eb1[idx];
        for (int k = 0; k < 16; k++) s += eeB[k] * ew1[l * 3072 + (32 + k) * 64 + j];
        c0[idx] = s;
    }
    if (t < 4) {
        float s = 0.f;
        for (int k = 0; k < 16; k++) s += eeW[t * 16 + k] * few[k];
        qw[t] = s;
    } else if (t == 4) {
        float s = feb[0];
        for (int k = 0; k < 16; k++) s += eeB[k] * few[k];
        qw[4] = s;
    }
}

// ---------------------------------------------------------------------------
// node init: x0 = leak*w+b ; zero deg, cursor, aggr
// ---------------------------------------------------------------------------
__global__ __launch_bounds__(256) void node_init_kernel(
    const float* __restrict__ leak, const float* __restrict__ nw, const float* __restrict__ nb,
    float* __restrict__ x0, float* __restrict__ aggr, int* __restrict__ deg, int* __restrict__ cur)
{
    int n = blockIdx.x * blockDim.x + threadIdx.x;
    if (n >= NN) return;
    float la = leak[n];
    float4* xo = reinterpret_cast<float4*>(x0 + n * 16);
    #pragma unroll
    for (int q4 = 0; q4 < 4; q4++) {
        float4 v;
        v.x = la * nw[q4 * 4 + 0] + nb[q4 * 4 + 0];
        v.y = la * nw[q4 * 4 + 1] + nb[q4 * 4 + 1];
        v.z = la * nw[q4 * 4 + 2] + nb[q4 * 4 + 2];
        v.w = la * nw[q4 * 4 + 3] + nb[q4 * 4 + 3];
        xo[q4] = v;
    }
    deg[n] = 0;
    cur[n] = 0;
    float4 z = {0.f, 0.f, 0.f, 0.f};
    float4* ap = reinterpret_cast<float4*>(aggr + n * 16);
    #pragma unroll
    for (int j = 0; j < 4; j++) ap[j] = z;
}

// ---------------------------------------------------------------------------
// edge init: q output (collapsed linear) + int degree histogram
// ---------------------------------------------------------------------------
__global__ __launch_bounds__(256) void edge_init_kernel(
    const float* __restrict__ pa, const int* __restrict__ dst,
    const float* __restrict__ qw, float* __restrict__ qout, int* __restrict__ deg)
{
    int t = blockIdx.x * blockDim.x + threadIdx.x;
    if (t >= NE) return;
    float4 p = reinterpret_cast<const float4*>(pa)[t];
    qout[t] = qw[4] + p.x * qw[0] + p.y * qw[1] + p.z * qw[2] + p.w * qw[3];
    atomicAdd(&deg[dst[t]], 1);
}

// ---------------------------------------------------------------------------
// single-block exclusive scan of deg[NN] -> off[NN+1]
// ---------------------------------------------------------------------------
#define SCAN_T 1024
#define SCAN_C 49   // 1024*49 = 50176 >= 50000
__global__ __launch_bounds__(SCAN_T) void scan_kernel(const int* __restrict__ deg, int* __restrict__ off)
{
    __shared__ int part[SCAN_T];
    int tid = threadIdx.x;
    int base = tid * SCAN_C;
    int s = 0;
    for (int i = 0; i < SCAN_C; i++) {
        int idx = base + i;
        if (idx < NN) s += deg[idx];
    }
    part[tid] = s;
    __syncthreads();
    for (int o = 1; o < SCAN_T; o <<= 1) {
        int v = (tid >= o) ? part[tid - o] : 0;
        __syncthreads();
        part[tid] += v;
        __syncthreads();
    }
    int run = part[tid] - s;   // exclusive prefix
    for (int i = 0; i < SCAN_C; i++) {
        int idx = base + i;
        if (idx < NN) { off[idx] = run; run += deg[idx]; }
    }
    if (tid == SCAN_T - 1) off[NN] = part[SCAN_T - 1];
}

// ---------------------------------------------------------------------------
// scatter: perm = edge ids sorted by dst (order within segment arbitrary)
// ---------------------------------------------------------------------------
__global__ __launch_bounds__(256) void scatter_kernel(
    const int* __restrict__ dst, const int* __restrict__ off,
    int* __restrict__ cur, int* __restrict__ perm)
{
    int t = blockIdx.x * blockDim.x + threadIdx.x;
    if (t >= NE) return;
    int d = dst[t];
    int pos = off[d] + atomicAdd(&cur[d], 1);
    perm[pos] = t;
}

// ---------------------------------------------------------------------------
// fused edge MLP + segmented aggregation.
// Phase 1: thread e (dst-sorted order) computes msg[16] = W2^T relu(W1*[xd,xs]+M*pa+c0)
//          -> LDS (stride 17 floats, conflict-free).
// Phase 2: block-local segment sums over contiguous dst ranges; one f32 atomic
//          partial per (node,k) per block into aggr[N][16].
// ---------------------------------------------------------------------------
__global__ __launch_bounds__(256) void edge_aggr_kernel(
    const float* __restrict__ x, const int* __restrict__ ei,
    const float* __restrict__ pa, const int* __restrict__ perm,
    const int* __restrict__ off,
    const float* __restrict__ w1t,  // [64][32]
    const float* __restrict__ Mm,   // [64][4]
    const float* __restrict__ c0,   // [64]
    const float* __restrict__ w2,   // [64][16]
    float* __restrict__ aggr)
{
    __shared__ float smsg[256 * 17];
    __shared__ int sdst[256];
    int tid = threadIdx.x;
    int ebase = blockIdx.x * 256;
    int e = ebase + tid;            // NE is an exact multiple of 256

    int t = perm[e];
    int s = ei[t];
    int d = ei[NE + t];
    sdst[tid] = d;

    float m[32];
    const float4* xd = reinterpret_cast<const float4*>(x + d * 16);
    const float4* xs = reinterpret_cast<const float4*>(x + s * 16);
    #pragma unroll
    for (int q4 = 0; q4 < 4; q4++) {
        float4 v = xd[q4];
        m[q4 * 4 + 0] = v.x; m[q4 * 4 + 1] = v.y; m[q4 * 4 + 2] = v.z; m[q4 * 4 + 3] = v.w;
    }
    #pragma unroll
    for (int q4 = 0; q4 < 4; q4++) {
        float4 v = xs[q4];
        m[16 + q4 * 4 + 0] = v.x; m[16 + q4 * 4 + 1] = v.y; m[16 + q4 * 4 + 2] = v.z; m[16 + q4 * 4 + 3] = v.w;
    }
    float4 p = reinterpret_cast<const float4*>(pa)[t];

    float msg[16];
    #pragma unroll
    for (int k = 0; k < 16; k++) msg[k] = 0.f;

    #pragma unroll 1
    for (int j0 = 0; j0 < 64; j0 += 8) {
        #pragma unroll
        for (int jj = 0; jj < 8; jj++) {
            int j = j0 + jj;
            float acc = c0[j] + p.x * Mm[j * 4 + 0] + p.y * Mm[j * 4 + 1]
                              + p.z * Mm[j * 4 + 2] + p.w * Mm[j * 4 + 3];
            const float* wr = w1t + j * 32;
            #pragma unroll
            for (int i = 0; i < 32; i++) acc += m[i] * wr[i];
            acc = fmaxf(acc, 0.f);
            const float* w2r = w2 + j * 16;
            #pragma unroll
            for (int k = 0; k < 16; k++) msg[k] += acc * w2r[k];
        }
    }
    #pragma unroll
    for (int k = 0; k < 16; k++) smsg[tid * 17 + k] = msg[k];
    __syncthreads();

    // phase 2
    int d_lo = sdst[0];
    int d_hi = sdst[255];
    int k = tid & 15;
    for (int n = d_lo + (tid >> 4); n <= d_hi; n += 16) {
        int s0 = off[n];
        int e0 = off[n + 1];
        if (s0 < ebase) s0 = ebase;
        if (e0 > ebase + 256) e0 = ebase + 256;
        if (s0 < e0) {
            float acc = 0.f;
            for (int i = s0; i < e0; i++) acc += smsg[(i - ebase) * 17 + k];
            unsafeAtomicAdd(&aggr[n * 16 + k], acc);
        }
    }
}

// ---------------------------------------------------------------------------
// node update: u = [x, aggr_sum/deg + b2 (0 if deg==0)], MLP 32->64->16.
// Re-zeros aggr for the next layer. Emits H on last layer.
// ---------------------------------------------------------------------------
__global__ __launch_bounds__(256) void node_mlp_kernel(
    const float* __restrict__ x, float* __restrict__ xn,
    float* __restrict__ aggr, const int* __restrict__ off,
    const float* __restrict__ eb2,
    const float* __restrict__ nw1t, const float* __restrict__ nb1,
    const float* __restrict__ nw2, const float* __restrict__ nb2,
    const float* __restrict__ fnw, const float* __restrict__ fnb,
    float* __restrict__ Hout, int writeH)
{
    int n = blockIdx.x * blockDim.x + threadIdx.x;
    if (n >= NN) return;
    float u[32];
    const float4* xp = reinterpret_cast<const float4*>(x + n * 16);
    #pragma unroll
    for (int q4 = 0; q4 < 4; q4++) {
        float4 v = xp[q4];
        u[q4 * 4 + 0] = v.x; u[q4 * 4 + 1] = v.y; u[q4 * 4 + 2] = v.z; u[q4 * 4 + 3] = v.w;
    }
    int dg = off[n + 1] - off[n];
    float inv = 1.0f / (float)(dg > 0 ? dg : 1);
    float bsc = (dg > 0) ? 1.0f : 0.0f;
    float4* ap = reinterpret_cast<float4*>(aggr + n * 16);
    float4 z = {0.f, 0.f, 0.f, 0.f};
    #pragma unroll
    for (int q4 = 0; q4 < 4; q4++) {
        float4 av = ap[q4];
        u[16 + q4 * 4 + 0] = av.x * inv + bsc * eb2[q4 * 4 + 0];
        u[16 + q4 * 4 + 1] = av.y * inv + bsc * eb2[q4 * 4 + 1];
        u[16 + q4 * 4 + 2] = av.z * inv + bsc * eb2[q4 * 4 + 2];
        u[16 + q4 * 4 + 3] = av.w * inv + bsc * eb2[q4 * 4 + 3];
        ap[q4] = z;   // re-zero for next layer
    }

    float o[16];
    #pragma unroll
    for (int k = 0; k < 16; k++) o[k] = nb2[k];
    #pragma unroll 1
    for (int j = 0; j < 64; j++) {
        float h = nb1[j];
        const float* wr = nw1t + j * 32;
        #pragma unroll
        for (int i = 0; i < 32; i++) h += u[i] * wr[i];
        h = fmaxf(h, 0.f);
        #pragma unroll
        for (int k = 0; k < 16; k++) o[k] += h * nw2[j * 16 + k];
    }
    float4* xo = reinterpret_cast<float4*>(xn + n * 16);
    #pragma unroll
    for (int q4 = 0; q4 < 4; q4++) {
        float4 v;
        v.x = o[q4 * 4 + 0]; v.y = o[q4 * 4 + 1]; v.z = o[q4 * 4 + 2]; v.w = o[q4 * 4 + 3];
        xo[q4] = v;
    }
    if (writeH) {
        float s = fnb[0];
        #pragma unroll
        for (int k = 0; k < 16; k++) s += o[k] * fnw[k];
        Hout[n] = s;
    }
}

extern "C" void kernel_launch(void* const* d_in, const int* in_sizes, int n_in,
                              void* d_out, int out_size, void* d_ws, size_t ws_size,
                              hipStream_t stream)
{
    const float* leak = (const float*)d_in[0];
    const float* pa   = (const float*)d_in[1];
    const int*   ei   = (const int*)d_in[2];
    const float* neww = (const float*)d_in[3];
    const float* newb = (const float*)d_in[4];
    const float* eeW  = (const float*)d_in[5];
    const float* eeB  = (const float*)d_in[6];
    const float* ew1  = (const float*)d_in[7];
    const float* eb1  = (const float*)d_in[8];
    const float* ew2  = (const float*)d_in[9];
    const float* eb2  = (const float*)d_in[10];
    const float* nw1  = (const float*)d_in[11];
    const float* nb1  = (const float*)d_in[12];
    const float* nw2  = (const float*)d_in[13];
    const float* nb2  = (const float*)d_in[14];
    const float* fnw  = (const float*)d_in[15];
    const float* fnb  = (const float*)d_in[16];
    const float* few  = (const float*)d_in[17];
    const float* feb  = (const float*)d_in[18];

    float* ws   = (float*)d_ws;
    float* x0   = ws + WS_X0;
    float* x1   = ws + WS_X1;
    float* aggr = ws + WS_AGGR;
    float* w1te = ws + WS_W1TE;
    float* Mm   = ws + WS_M;
    float* c0   = ws + WS_C0;
    float* w1tn = ws + WS_W1TN;
    float* qw   = ws + WS_QW;
    int*   wi   = (int*)(ws + WS_IEND);
    int*   deg  = wi + WI_DEG;
    int*   cur  = wi + WI_CUR;
    int*   off  = wi + WI_OFF;
    int*   perm = wi + WI_PERM;

    float* H = (float*)d_out;
    float* q = (float*)d_out + NN;
    const int* dstp = ei + NE;

    prep_kernel<<<8, 256, 0, stream>>>(ew1, eb1, nw1, eeW, eeB, few, feb,
                                       w1te, Mm, c0, w1tn, qw);
    node_init_kernel<<<(NN + 255) / 256, 256, 0, stream>>>(leak, neww, newb, x0, aggr, deg, cur);
    edge_init_kernel<<<(NE + 255) / 256, 256, 0, stream>>>(pa, dstp, qw, q, deg);
    scan_kernel<<<1, SCAN_T, 0, stream>>>(deg, off);
    scatter_kernel<<<(NE + 255) / 256, 256, 0, stream>>>(dstp, off, cur, perm);

    float* xcur = x0;
    float* xnxt = x1;
    for (int l = 0; l < 3; l++) {
        edge_aggr_kernel<<<NE / 256, 256, 0, stream>>>(
            xcur, ei, pa, perm, off, w1te + l * 2048, Mm + l * 256, c0 + l * 64,
            ew2 + l * 1024, aggr);
        node_mlp_kernel<<<(NN + 255) / 256, 256, 0, stream>>>(
            xcur, xnxt, aggr, off, eb2 + l * 16,
            w1tn + l * 2048, nb1 + l * 64, nw2 + l * 1024, nb2 + l * 16,
            fnw, fnb, H, (l == 2) ? 1 : 0);
        float* tmp = xcur; xcur = xnxt; xnxt = tmp;
    }
}